// Round 1
// baseline (169.550 us; speedup 1.0000x reference)
//
#include <hip/hip_runtime.h>

// ---------- types ----------
typedef __bf16 bf16;
typedef __bf16 bf16x4 __attribute__((ext_vector_type(4)));
typedef __bf16 bf16x8 __attribute__((ext_vector_type(8)));
typedef float f32x4 __attribute__((ext_vector_type(4)));

#define ALPHA_ 0.125f   // 1/sqrt(64)

// sizes
// H=8 heads, B=16, N=512, HID=512, D=64, M = B*N = 8192
// ws layout (bytes):
//   xb    [8192][512] bf16             @ 0          (8,388,608)
//   wcat  [1536][512] bf16 (B^T)       @ 8388608    (1,572,864)
//   wot   [512][512]  bf16 (Wo^T)      @ 9961472    (524,288)
//   Q     [8][8192][64] bf16           @ 10485760   (8,388,608)
//   K     [8][8192][64] bf16           @ 18874368   (8,388,608)
//   Vt    [8][16][64][512] bf16        @ 27262976   (8,388,608)
//   Oatt  [8192][512] bf16             @ 35651584   (8,388,608)
// total 44,040,192 bytes

__device__ __forceinline__ void gload16(const void* g, void* l) {
  __builtin_amdgcn_global_load_lds((__attribute__((address_space(1))) void*)(g),
                                   (__attribute__((address_space(3))) void*)(l),
                                   16, 0, 0);
}

// ---------- prep kernels ----------
__global__ void cast_x_kernel(const float* __restrict__ x, bf16* __restrict__ xb) {
  int i = blockIdx.x * 256 + threadIdx.x;          // 1,048,576 threads, 4 elems each
  float4 v = ((const float4*)x)[i];
  bf16x4 o = {(bf16)v.x, (bf16)v.y, (bf16)v.z, (bf16)v.w};
  ((bf16x4*)xb)[i] = o;
}

__global__ void prep_w_kernel(const float* __restrict__ Wq, const float* __restrict__ Wk,
                              const float* __restrict__ Wv, bf16* __restrict__ wcat) {
  int i = blockIdx.x * 256 + threadIdx.x;          // 786,432 = 1536*512
  int h = i & 511, j = i >> 9;
  int qkv = j >> 9, g = (j >> 6) & 7, d = j & 63;
  const float* W = (qkv == 0) ? Wq : ((qkv == 1) ? Wk : Wv);
  wcat[i] = (bf16)W[((g << 9) + h) * 64 + d];      // wcat[j][h] = W[g][h][d]
}

__global__ void prep_wo_kernel(const float* __restrict__ Wo, bf16* __restrict__ wot) {
  int i = blockIdx.x * 256 + threadIdx.x;          // 262,144
  int k = i & 511, n = i >> 9;
  wot[i] = (bf16)Wo[(k << 9) + n];                 // wot[n][k] = Wo[k][n]
}

// ---------- GEMM: C = A[M,K] * Bt[N,K]^T, bf16 in, f32 acc ----------
// 128x128 tile, BK=32, 256 threads (4 waves, each 64x64 = 4x4 frags of 16x16)
// MODE 0: QKV epilogue (decode col -> Q/K/Vt bf16 scatter)
// MODE 1: plain f32 C write
template <int MODE>
__global__ __launch_bounds__(256, 2) void gemm_bt_kernel(
    const bf16* __restrict__ A, const bf16* __restrict__ Bt, int Kdim, int Ndim,
    float* __restrict__ Cf, bf16* __restrict__ Qo, bf16* __restrict__ Ko,
    bf16* __restrict__ Vto) {
  __shared__ bf16 lA[128 * 32];
  __shared__ bf16 lB[128 * 32];
  const int t = threadIdx.x;
  const int w = t >> 6;
  const int lane = t & 63;
  const int lhi = lane >> 4, llo = lane & 15;
  const int m0 = blockIdx.y * 128, n0 = blockIdx.x * 128;
  const int wr = (w >> 1) * 64, wc = (w & 1) * 64;

  f32x4 acc[4][4] = {};
  const int nkt = Kdim >> 5;
  for (int kt = 0; kt < nkt; ++kt) {
#pragma unroll
    for (int c = 0; c < 2; ++c) {
      int u = c * 256 + t;
      const bf16* ga = A + (size_t)(m0 + (u >> 2)) * Kdim + kt * 32 + (u & 3) * 8;
      gload16(ga, &lA[c * 2048 + w * 512]);
      const bf16* gb = Bt + (size_t)(n0 + (u >> 2)) * Kdim + kt * 32 + (u & 3) * 8;
      gload16(gb, &lB[c * 2048 + w * 512]);
    }
    __syncthreads();
    bf16x8 af[4], bfr[4];
#pragma unroll
    for (int i = 0; i < 4; ++i) {
      af[i] = *(const bf16x8*)&lA[(wr + i * 16 + llo) * 32 + lhi * 8];
      bfr[i] = *(const bf16x8*)&lB[(wc + i * 16 + llo) * 32 + lhi * 8];
    }
#pragma unroll
    for (int i = 0; i < 4; ++i)
#pragma unroll
      for (int j = 0; j < 4; ++j)
        acc[i][j] = __builtin_amdgcn_mfma_f32_16x16x32_bf16(af[i], bfr[j], acc[i][j], 0, 0, 0);
    __syncthreads();
  }

#pragma unroll
  for (int i = 0; i < 4; ++i) {
    int row = m0 + wr + i * 16 + lhi * 4;
#pragma unroll
    for (int j = 0; j < 4; ++j) {
      int col = n0 + wc + j * 16 + llo;
#pragma unroll
      for (int r = 0; r < 4; ++r) {
        float v = acc[i][j][r];
        int rr = row + r;
        if (MODE == 0) {
          int qkv = col >> 9, g = (col >> 6) & 7, d = col & 63;
          bf16 bv = (bf16)v;
          if (qkv == 0)
            Qo[((size_t)g * 8192 + rr) * 64 + d] = bv;
          else if (qkv == 1)
            Ko[((size_t)g * 8192 + rr) * 64 + d] = bv;
          else {
            int b = rr >> 9, n = rr & 511;
            Vto[(((size_t)g * 16 + b) * 64 + d) * 512 + n] = bv;
          }
        } else {
          Cf[(size_t)rr * Ndim + col] = v;
        }
      }
    }
  }
}

// ---------- fused attention ----------
// grid (4 qtiles, 16 batch, 8 heads), 256 threads (4 waves x 32 q-rows)
__global__ __launch_bounds__(256, 2) void attn_kernel(
    const bf16* __restrict__ Qa, const bf16* __restrict__ Ka,
    const bf16* __restrict__ Vta, const float* __restrict__ edge,
    bf16* __restrict__ Oatt) {
  __shared__ bf16 lKP[16384];  // K tile [128][64] (first 8192) / later P [4][32][128]
  __shared__ bf16 lV[8192];    // V^T tile [64][128]
  const int t = threadIdx.x, w = t >> 6, lane = t & 63;
  const int lhi = lane >> 4, llo = lane & 15;
  const int qt = blockIdx.x, b = blockIdx.y, g = blockIdx.z;
  const int q0 = qt * 128 + w * 32;
  const bf16* Qg = Qa + ((size_t)g * 8192 + b * 512) * 64;
  const bf16* Kg = Ka + ((size_t)g * 8192 + b * 512) * 64;
  const bf16* Vg = Vta + ((size_t)g * 16 + b) * (64 * 512);
  const float* eg = edge + ((size_t)g * 16 + b) * (512 * 512);

  // Q fragments in registers: [mi][ks]
  bf16x8 qf[2][2];
#pragma unroll
  for (int mi = 0; mi < 2; ++mi)
#pragma unroll
    for (int ks = 0; ks < 2; ++ks)
      qf[mi][ks] = *(const bf16x8*)(Qg + (size_t)(q0 + mi * 16 + llo) * 64 + ks * 32 + lhi * 8);

  f32x4 oacc[2][4] = {};
  float mrow[2][4], lrow[2][4];
#pragma unroll
  for (int mi = 0; mi < 2; ++mi)
#pragma unroll
    for (int r = 0; r < 4; ++r) {
      mrow[mi][r] = -1e30f;
      lrow[mi][r] = 0.f;
    }

  for (int kv0 = 0; kv0 < 512; kv0 += 128) {
    // stage K [128][64] and V^T [64][128] (XOR-swizzled rows)
#pragma unroll
    for (int c = 0; c < 4; ++c) {
      int u = c * 256 + t;
      int kr = u >> 3, kc = (u & 7) * 8;
      bf16x8 kvv = *(const bf16x8*)(Kg + (size_t)(kv0 + kr) * 64 + kc);
      *(bf16x8*)&lKP[(kr * 64 + kc) ^ ((kr & 7) << 3)] = kvv;
      int vr = u >> 4, vc = (u & 15) * 8;
      bf16x8 vv = *(const bf16x8*)(Vg + (size_t)vr * 512 + kv0 + vc);
      *(bf16x8*)&lV[(vr * 128 + vc) ^ ((vr & 7) << 3)] = vv;
    }
    __syncthreads();

    // S = Q K^T (alpha applied later), frags [2 mi][8 ni]
    f32x4 sc[2][8] = {};
#pragma unroll
    for (int ks = 0; ks < 2; ++ks) {
      bf16x8 kf[8];
#pragma unroll
      for (int ni = 0; ni < 8; ++ni) {
        int row = ni * 16 + llo;
        kf[ni] = *(const bf16x8*)&lKP[(row * 64 + ks * 32 + lhi * 8) ^ ((row & 7) << 3)];
      }
#pragma unroll
      for (int mi = 0; mi < 2; ++mi)
#pragma unroll
        for (int ni = 0; ni < 8; ++ni)
          sc[mi][ni] = __builtin_amdgcn_mfma_f32_16x16x32_bf16(qf[mi][ks], kf[ni], sc[mi][ni], 0, 0, 0);
    }

    // edge add + online softmax (rows owned by 16-lane groups; shfl_xor reduce)
    float scl[2][4];
#pragma unroll
    for (int mi = 0; mi < 2; ++mi) {
#pragma unroll
      for (int r = 0; r < 4; ++r) {
        int qrow = q0 + mi * 16 + lhi * 4 + r;
        const float* ep = eg + (size_t)qrow * 512 + kv0 + llo;
        float mx = -1e30f;
#pragma unroll
        for (int ni = 0; ni < 8; ++ni) {
          float sv = fmaf(ALPHA_, sc[mi][ni][r], ep[ni * 16]);
          sc[mi][ni][r] = sv;
          mx = fmaxf(mx, sv);
        }
        mx = fmaxf(mx, __shfl_xor(mx, 1));
        mx = fmaxf(mx, __shfl_xor(mx, 2));
        mx = fmaxf(mx, __shfl_xor(mx, 4));
        mx = fmaxf(mx, __shfl_xor(mx, 8));
        float mold = mrow[mi][r];
        float mnew = fmaxf(mold, mx);
        float s = __expf(mold - mnew);
        mrow[mi][r] = mnew;
        scl[mi][r] = s;
        float rsum = 0.f;
#pragma unroll
        for (int ni = 0; ni < 8; ++ni) {
          float p = __expf(sc[mi][ni][r] - mnew);
          sc[mi][ni][r] = p;
          rsum += p;
        }
        rsum += __shfl_xor(rsum, 1);
        rsum += __shfl_xor(rsum, 2);
        rsum += __shfl_xor(rsum, 4);
        rsum += __shfl_xor(rsum, 8);
        lrow[mi][r] = lrow[mi][r] * s + rsum;
      }
    }
#pragma unroll
    for (int mi = 0; mi < 2; ++mi)
#pragma unroll
      for (int nc = 0; nc < 4; ++nc)
#pragma unroll
        for (int r = 0; r < 4; ++r) oacc[mi][nc][r] *= scl[mi][r];

    __syncthreads();  // all waves done reading K tile before P overwrites it

    // write P (bf16) into per-wave LDS region (unioned with K tile)
    bf16* Pw = &lKP[w * 4096];
#pragma unroll
    for (int mi = 0; mi < 2; ++mi)
#pragma unroll
      for (int ni = 0; ni < 8; ++ni)
#pragma unroll
        for (int r = 0; r < 4; ++r) {
          int row = mi * 16 + lhi * 4 + r;
          Pw[(row * 128 + ni * 16 + llo) ^ ((row & 7) << 3)] = (bf16)sc[mi][ni][r];
        }

    // O += P V
#pragma unroll
    for (int ks2 = 0; ks2 < 4; ++ks2) {
      bf16x8 pf[2], vf[4];
#pragma unroll
      for (int mi = 0; mi < 2; ++mi) {
        int row = mi * 16 + llo;
        pf[mi] = *(const bf16x8*)&Pw[(row * 128 + ks2 * 32 + lhi * 8) ^ ((row & 7) << 3)];
      }
#pragma unroll
      for (int nc = 0; nc < 4; ++nc) {
        int row = nc * 16 + llo;
        vf[nc] = *(const bf16x8*)&lV[(row * 128 + ks2 * 32 + lhi * 8) ^ ((row & 7) << 3)];
      }
#pragma unroll
      for (int mi = 0; mi < 2; ++mi)
#pragma unroll
        for (int nc = 0; nc < 4; ++nc)
          oacc[mi][nc] = __builtin_amdgcn_mfma_f32_16x16x32_bf16(pf[mi], vf[nc], oacc[mi][nc], 0, 0, 0);
    }
    __syncthreads();  // before next iteration restages lKP/lV
  }

  // normalize + write Oatt [b*512+q][g*64+d]
#pragma unroll
  for (int mi = 0; mi < 2; ++mi)
#pragma unroll
    for (int nc = 0; nc < 4; ++nc)
#pragma unroll
      for (int r = 0; r < 4; ++r) {
        int qrow = q0 + mi * 16 + lhi * 4 + r;
        float ov = oacc[mi][nc][r] / lrow[mi][r];
        Oatt[((size_t)b * 512 + qrow) * 512 + g * 64 + nc * 16 + llo] = (bf16)ov;
      }
}

// ---------- launch ----------
extern "C" void kernel_launch(void* const* d_in, const int* in_sizes, int n_in,
                              void* d_out, int out_size, void* d_ws, size_t ws_size,
                              hipStream_t stream) {
  (void)in_sizes; (void)n_in; (void)out_size; (void)ws_size;
  const float* x = (const float*)d_in[0];
  const float* edge = (const float*)d_in[1];
  const float* Wq = (const float*)d_in[2];
  const float* Wk = (const float*)d_in[3];
  const float* Wv = (const float*)d_in[4];
  const float* Wo = (const float*)d_in[5];
  float* out = (float*)d_out;

  char* ws = (char*)d_ws;
  bf16* xb   = (bf16*)(ws + 0);
  bf16* wcat = (bf16*)(ws + 8388608);
  bf16* wot  = (bf16*)(ws + 9961472);
  bf16* Qa   = (bf16*)(ws + 10485760);
  bf16* Ka   = (bf16*)(ws + 18874368);
  bf16* Vta  = (bf16*)(ws + 27262976);
  bf16* Oatt = (bf16*)(ws + 35651584);

  cast_x_kernel<<<4096, 256, 0, stream>>>(x, xb);
  prep_w_kernel<<<3072, 256, 0, stream>>>(Wq, Wk, Wv, wcat);
  prep_wo_kernel<<<1024, 256, 0, stream>>>(Wo, wot);

  // QKV: A=xb [8192,512], Bt=wcat [1536,512]
  gemm_bt_kernel<0><<<dim3(12, 64), 256, 0, stream>>>(xb, wcat, 512, 1536,
                                                      nullptr, Qa, Ka, Vta);
  // fused attention
  attn_kernel<<<dim3(4, 16, 8), 256, 0, stream>>>(Qa, Ka, Vta, edge, Oatt);
  // output projection: A=Oatt [8192,512], Bt=wot [512,512] -> f32 out
  gemm_bt_kernel<1><<<dim3(4, 64), 256, 0, stream>>>(Oatt, wot, 512, 512,
                                                     out, nullptr, nullptr, nullptr);
}

// Round 2
// 116.463 us; speedup vs baseline: 1.4558x; 1.4558x over previous
//
#include <hip/hip_runtime.h>

// ---------- types ----------
typedef __bf16 bf16;
typedef __bf16 bf16x4 __attribute__((ext_vector_type(4)));
typedef __bf16 bf16x8 __attribute__((ext_vector_type(8)));
typedef float f32x4 __attribute__((ext_vector_type(4)));

#define ALPHA_ 0.125f   // 1/sqrt(64)

// sizes
// H=8 heads, B=16, N=512, HID=512, D=64, M = B*N = 8192
// ws layout (bytes):
//   xb    [8192][512] bf16             @ 0          (8,388,608)
//   wcat  [1536][512] bf16 (B^T)       @ 8388608    (1,572,864)
//   wot   [512][512]  bf16 (Wo^T)      @ 9961472    (524,288)
//   Q     [8][8192][64] bf16           @ 10485760   (8,388,608)
//   K     [8][8192][64] bf16           @ 18874368   (8,388,608)
//   Vt    [8][16][64][512] bf16        @ 27262976   (8,388,608)
//   Oatt  [8192][512] bf16             @ 35651584   (8,388,608)
// total 44,040,192 bytes

__device__ __forceinline__ void gload16(const void* g, void* l) {
  __builtin_amdgcn_global_load_lds((__attribute__((address_space(1))) void*)(g),
                                   (__attribute__((address_space(3))) void*)(l),
                                   16, 0, 0);
}

// ---------- prep kernels ----------
__global__ void cast_x_kernel(const float* __restrict__ x, bf16* __restrict__ xb) {
  int i = blockIdx.x * 256 + threadIdx.x;          // 1,048,576 threads, 4 elems each
  float4 v = ((const float4*)x)[i];
  bf16x4 o = {(bf16)v.x, (bf16)v.y, (bf16)v.z, (bf16)v.w};
  ((bf16x4*)xb)[i] = o;
}

__global__ void prep_w_kernel(const float* __restrict__ Wq, const float* __restrict__ Wk,
                              const float* __restrict__ Wv, bf16* __restrict__ wcat) {
  int i = blockIdx.x * 256 + threadIdx.x;          // 786,432 = 1536*512
  int h = i & 511, j = i >> 9;
  int qkv = j >> 9, g = (j >> 6) & 7, d = j & 63;
  const float* W = (qkv == 0) ? Wq : ((qkv == 1) ? Wk : Wv);
  wcat[i] = (bf16)W[((g << 9) + h) * 64 + d];      // wcat[j][h] = W[g][h][d]
}

__global__ void prep_wo_kernel(const float* __restrict__ Wo, bf16* __restrict__ wot) {
  int i = blockIdx.x * 256 + threadIdx.x;          // 262,144
  int k = i & 511, n = i >> 9;
  wot[i] = (bf16)Wo[(k << 9) + n];                 // wot[n][k] = Wo[k][n]
}

// ---------- GEMM: C = A[M,K] * Bt[N,K]^T, bf16 in, f32 acc ----------
// 128x128 tile, BK=32, 256 threads (4 waves, each 64x64 = 4x4 frags of 16x16)
// MODE 0: QKV epilogue (decode col -> Q/K/Vt bf16 scatter)
// MODE 1: plain f32 C write
template <int MODE>
__global__ __launch_bounds__(256, 2) void gemm_bt_kernel(
    const bf16* __restrict__ A, const bf16* __restrict__ Bt, int Kdim, int Ndim,
    float* __restrict__ Cf, bf16* __restrict__ Qo, bf16* __restrict__ Ko,
    bf16* __restrict__ Vto) {
  __shared__ bf16 lA[128 * 32];
  __shared__ bf16 lB[128 * 32];
  const int t = threadIdx.x;
  const int w = t >> 6;
  const int lane = t & 63;
  const int lhi = lane >> 4, llo = lane & 15;
  const int m0 = blockIdx.y * 128, n0 = blockIdx.x * 128;
  const int wr = (w >> 1) * 64, wc = (w & 1) * 64;

  f32x4 acc[4][4] = {};
  const int nkt = Kdim >> 5;
  for (int kt = 0; kt < nkt; ++kt) {
#pragma unroll
    for (int c = 0; c < 2; ++c) {
      int u = c * 256 + t;
      const bf16* ga = A + (size_t)(m0 + (u >> 2)) * Kdim + kt * 32 + (u & 3) * 8;
      gload16(ga, &lA[c * 2048 + w * 512]);
      const bf16* gb = Bt + (size_t)(n0 + (u >> 2)) * Kdim + kt * 32 + (u & 3) * 8;
      gload16(gb, &lB[c * 2048 + w * 512]);
    }
    __syncthreads();
    bf16x8 af[4], bfr[4];
#pragma unroll
    for (int i = 0; i < 4; ++i) {
      af[i] = *(const bf16x8*)&lA[(wr + i * 16 + llo) * 32 + lhi * 8];
      bfr[i] = *(const bf16x8*)&lB[(wc + i * 16 + llo) * 32 + lhi * 8];
    }
#pragma unroll
    for (int i = 0; i < 4; ++i)
#pragma unroll
      for (int j = 0; j < 4; ++j)
        acc[i][j] = __builtin_amdgcn_mfma_f32_16x16x32_bf16(af[i], bfr[j], acc[i][j], 0, 0, 0);
    __syncthreads();
  }

#pragma unroll
  for (int i = 0; i < 4; ++i) {
    int row = m0 + wr + i * 16 + lhi * 4;
#pragma unroll
    for (int j = 0; j < 4; ++j) {
      int col = n0 + wc + j * 16 + llo;
#pragma unroll
      for (int r = 0; r < 4; ++r) {
        float v = acc[i][j][r];
        int rr = row + r;
        if (MODE == 0) {
          int qkv = col >> 9, g = (col >> 6) & 7, d = col & 63;
          bf16 bv = (bf16)v;
          if (qkv == 0)
            Qo[((size_t)g * 8192 + rr) * 64 + d] = bv;
          else if (qkv == 1)
            Ko[((size_t)g * 8192 + rr) * 64 + d] = bv;
          else {
            int b = rr >> 9, n = rr & 511;
            Vto[(((size_t)g * 16 + b) * 64 + d) * 512 + n] = bv;
          }
        } else {
          Cf[(size_t)rr * Ndim + col] = v;
        }
      }
    }
  }
}

// ---------- fused attention ----------
// grid (4 qtiles, 16 batch, 8 heads), 256 threads (4 waves x 32 q-rows)
// S^T trick: compute mfma(K, Q) so each lane owns q-row (llo) with 4
// contiguous k-columns per fragment reg -> edge bias loads become float4.
__global__ __launch_bounds__(256, 2) void attn_kernel(
    const bf16* __restrict__ Qa, const bf16* __restrict__ Ka,
    const bf16* __restrict__ Vta, const float* __restrict__ edge,
    bf16* __restrict__ Oatt) {
  __shared__ bf16 lK[128 * 64];    // K tile [128][64] swizzled
  __shared__ bf16 lV[64 * 128];    // V^T tile [64][128] swizzled
  __shared__ bf16 lP[4][32 * 128]; // per-wave P [32][128] swizzled
  const int t = threadIdx.x, w = t >> 6, lane = t & 63;
  const int lhi = lane >> 4, llo = lane & 15;
  const int qt = blockIdx.x, b = blockIdx.y, g = blockIdx.z;
  const int q0 = qt * 128 + w * 32;
  const bf16* Qg = Qa + ((size_t)g * 8192 + b * 512) * 64;
  const bf16* Kg = Ka + ((size_t)g * 8192 + b * 512) * 64;
  const bf16* Vg = Vta + ((size_t)g * 16 + b) * (64 * 512);
  const float* eg = edge + ((size_t)g * 16 + b) * (512 * 512);

  // Q fragments in registers: [mi][ks]  (B-operand layout: lane col=llo=q)
  bf16x8 qf[2][2];
#pragma unroll
  for (int mi = 0; mi < 2; ++mi)
#pragma unroll
    for (int ks = 0; ks < 2; ++ks)
      qf[mi][ks] = *(const bf16x8*)(Qg + (size_t)(q0 + mi * 16 + llo) * 64 + ks * 32 + lhi * 8);

  f32x4 oacc[2][4] = {};
  float mrow[2] = {-1e30f, -1e30f};
  float lrow[2] = {0.f, 0.f};

  for (int kv0 = 0; kv0 < 512; kv0 += 128) {
    // ---- issue ALL loads for this tile up front (drained at the barrier) ----
    // stage K [128][64] and V^T [64][128] (XOR-swizzled rows), reg->LDS
#pragma unroll
    for (int c = 0; c < 4; ++c) {
      int u = c * 256 + t;
      int kr = u >> 3, kc = (u & 7) * 8;
      bf16x8 kvv = *(const bf16x8*)(Kg + (size_t)(kv0 + kr) * 64 + kc);
      *(bf16x8*)&lK[(kr * 64 + kc) ^ ((kr & 7) << 3)] = kvv;
      int vr = u >> 4, vc = (u & 15) * 8;
      bf16x8 vv = *(const bf16x8*)(Vg + (size_t)vr * 512 + kv0 + vc);
      *(bf16x8*)&lV[(vr * 128 + vc) ^ ((vr & 7) << 3)] = vv;
    }
    // edge bias: float4 per (mi,ni) -> 16 loads, 256 B/thread in flight
    f32x4 ef[2][8];
#pragma unroll
    for (int mi = 0; mi < 2; ++mi)
#pragma unroll
      for (int ni = 0; ni < 8; ++ni)
        ef[mi][ni] = *(const f32x4*)(eg + (size_t)(q0 + mi * 16 + llo) * 512 + kv0 + ni * 16 + lhi * 4);
    __syncthreads();

    // ---- S^T = K Q^T : sc[mi][ni][r] = S[q=mi*16+llo][k=ni*16+lhi*4+r] ----
    f32x4 sc[2][8] = {};
#pragma unroll
    for (int ks = 0; ks < 2; ++ks) {
      bf16x8 kf[8];
#pragma unroll
      for (int ni = 0; ni < 8; ++ni) {
        int row = ni * 16 + llo;
        kf[ni] = *(const bf16x8*)&lK[(row * 64 + ks * 32 + lhi * 8) ^ ((row & 7) << 3)];
      }
#pragma unroll
      for (int mi = 0; mi < 2; ++mi)
#pragma unroll
        for (int ni = 0; ni < 8; ++ni)
          sc[mi][ni] = __builtin_amdgcn_mfma_f32_16x16x32_bf16(kf[ni], qf[mi][ks], sc[mi][ni], 0, 0, 0);
    }

    // ---- edge add + online softmax (reduce over lhi axis: 2 shfls) ----
    float sscale[2];
#pragma unroll
    for (int mi = 0; mi < 2; ++mi) {
      float mx = -1e30f;
#pragma unroll
      for (int ni = 0; ni < 8; ++ni)
#pragma unroll
        for (int r = 0; r < 4; ++r) {
          float sv = fmaf(ALPHA_, sc[mi][ni][r], ef[mi][ni][r]);
          sc[mi][ni][r] = sv;
          mx = fmaxf(mx, sv);
        }
      mx = fmaxf(mx, __shfl_xor(mx, 16));
      mx = fmaxf(mx, __shfl_xor(mx, 32));
      float mnew = fmaxf(mrow[mi], mx);
      float s = __expf(mrow[mi] - mnew);
      mrow[mi] = mnew;
      sscale[mi] = s;
      float rsum = 0.f;
#pragma unroll
      for (int ni = 0; ni < 8; ++ni)
#pragma unroll
        for (int r = 0; r < 4; ++r) {
          float p = __expf(sc[mi][ni][r] - mnew);
          sc[mi][ni][r] = p;
          rsum += p;
        }
      rsum += __shfl_xor(rsum, 16);
      rsum += __shfl_xor(rsum, 32);
      lrow[mi] = lrow[mi] * s + rsum;
    }

    // rescale O accumulator: redistribute s from owner lane (llo=q) to C-layout lanes
#pragma unroll
    for (int mi = 0; mi < 2; ++mi) {
#pragma unroll
      for (int r = 0; r < 4; ++r) {
        float sq = __shfl(sscale[mi], (lane & 48) | (lhi * 4 + r));
#pragma unroll
        for (int nc = 0; nc < 4; ++nc) oacc[mi][nc][r] *= sq;
      }
    }

    // ---- write P (bf16x4 packed) into per-wave LDS (no barrier needed) ----
    bf16* Pw = lP[w];
#pragma unroll
    for (int mi = 0; mi < 2; ++mi)
#pragma unroll
      for (int ni = 0; ni < 8; ++ni) {
        int row = mi * 16 + llo;
        int colb = ni * 16 + lhi * 4;
        bf16x4 pv = {(bf16)sc[mi][ni][0], (bf16)sc[mi][ni][1],
                     (bf16)sc[mi][ni][2], (bf16)sc[mi][ni][3]};
        *(bf16x4*)&Pw[(row * 128 + colb) ^ ((row & 7) << 3)] = pv;
      }

    // ---- O += P V ----
#pragma unroll
    for (int ks2 = 0; ks2 < 4; ++ks2) {
      bf16x8 pf[2], vf[4];
#pragma unroll
      for (int mi = 0; mi < 2; ++mi) {
        int row = mi * 16 + llo;
        pf[mi] = *(const bf16x8*)&Pw[(row * 128 + ks2 * 32 + lhi * 8) ^ ((row & 7) << 3)];
      }
#pragma unroll
      for (int nc = 0; nc < 4; ++nc) {
        int row = nc * 16 + llo;
        vf[nc] = *(const bf16x8*)&lV[(row * 128 + ks2 * 32 + lhi * 8) ^ ((row & 7) << 3)];
      }
#pragma unroll
      for (int mi = 0; mi < 2; ++mi)
#pragma unroll
        for (int nc = 0; nc < 4; ++nc)
          oacc[mi][nc] = __builtin_amdgcn_mfma_f32_16x16x32_bf16(pf[mi], vf[nc], oacc[mi][nc], 0, 0, 0);
    }
    __syncthreads();  // before next iteration restages lK/lV
  }

  // normalize (redistribute 1/lrow to C-layout lanes) + write Oatt
#pragma unroll
  for (int mi = 0; mi < 2; ++mi) {
    float rcpl = 1.0f / lrow[mi];
#pragma unroll
    for (int r = 0; r < 4; ++r) {
      float lr = __shfl(rcpl, (lane & 48) | (lhi * 4 + r));
      int qrow = q0 + mi * 16 + lhi * 4 + r;
#pragma unroll
      for (int nc = 0; nc < 4; ++nc) {
        float ov = oacc[mi][nc][r] * lr;
        Oatt[((size_t)b * 512 + qrow) * 512 + g * 64 + nc * 16 + llo] = (bf16)ov;
      }
    }
  }
}

// ---------- launch ----------
extern "C" void kernel_launch(void* const* d_in, const int* in_sizes, int n_in,
                              void* d_out, int out_size, void* d_ws, size_t ws_size,
                              hipStream_t stream) {
  (void)in_sizes; (void)n_in; (void)out_size; (void)ws_size;
  const float* x = (const float*)d_in[0];
  const float* edge = (const float*)d_in[1];
  const float* Wq = (const float*)d_in[2];
  const float* Wk = (const float*)d_in[3];
  const float* Wv = (const float*)d_in[4];
  const float* Wo = (const float*)d_in[5];
  float* out = (float*)d_out;

  char* ws = (char*)d_ws;
  bf16* xb   = (bf16*)(ws + 0);
  bf16* wcat = (bf16*)(ws + 8388608);
  bf16* wot  = (bf16*)(ws + 9961472);
  bf16* Qa   = (bf16*)(ws + 10485760);
  bf16* Ka   = (bf16*)(ws + 18874368);
  bf16* Vta  = (bf16*)(ws + 27262976);
  bf16* Oatt = (bf16*)(ws + 35651584);

  cast_x_kernel<<<4096, 256, 0, stream>>>(x, xb);
  prep_w_kernel<<<3072, 256, 0, stream>>>(Wq, Wk, Wv, wcat);
  prep_wo_kernel<<<1024, 256, 0, stream>>>(Wo, wot);

  // QKV: A=xb [8192,512], Bt=wcat [1536,512]
  gemm_bt_kernel<0><<<dim3(12, 64), 256, 0, stream>>>(xb, wcat, 512, 1536,
                                                      nullptr, Qa, Ka, Vta);
  // fused attention
  attn_kernel<<<dim3(4, 16, 8), 256, 0, stream>>>(Qa, Ka, Vta, edge, Oatt);
  // output projection: A=Oatt [8192,512], Bt=wot [512,512] -> f32 out
  gemm_bt_kernel<1><<<dim3(4, 64), 256, 0, stream>>>(Oatt, wot, 512, 512,
                                                     out, nullptr, nullptr, nullptr);
}

// Round 3
// 108.146 us; speedup vs baseline: 1.5678x; 1.0769x over previous
//
#include <hip/hip_runtime.h>

// ---------- types ----------
typedef __bf16 bf16;
typedef __bf16 bf16x4 __attribute__((ext_vector_type(4)));
typedef __bf16 bf16x8 __attribute__((ext_vector_type(8)));
typedef float f32x4 __attribute__((ext_vector_type(4)));

#define ALPHA_ 0.125f   // 1/sqrt(64)

// H=8 heads, B=16, N=512, HID=512, D=64, M = B*N = 8192
// ws layout (bytes):
//   xb    [8192][512] bf16             @ 0          (8,388,608)
//   wcat  [1536][512] bf16 (B^T)       @ 8388608    (1,572,864)
//   wot   [512][512]  bf16 (Wo^T)      @ 9961472    (524,288)
//   Q     [8][8192][64] bf16           @ 10485760   (8,388,608)
//   K     [8][8192][64] bf16           @ 18874368   (8,388,608)
//   Vt    [8][16][64][512] bf16        @ 27262976   (8,388,608)
//   Oatt  [8192][512] bf16             @ 35651584   (8,388,608)

__device__ __forceinline__ void gload16(const void* g, void* l) {
  __builtin_amdgcn_global_load_lds((__attribute__((address_space(1))) void*)(g),
                                   (__attribute__((address_space(3))) void*)(l),
                                   16, 0, 0);
}

// ---------- prep kernels ----------
__global__ void cast_x_kernel(const float* __restrict__ x, bf16* __restrict__ xb) {
  int i = blockIdx.x * 256 + threadIdx.x;
  float4 v = ((const float4*)x)[i];
  bf16x4 o = {(bf16)v.x, (bf16)v.y, (bf16)v.z, (bf16)v.w};
  ((bf16x4*)xb)[i] = o;
}

__global__ void prep_w_kernel(const float* __restrict__ Wq, const float* __restrict__ Wk,
                              const float* __restrict__ Wv, bf16* __restrict__ wcat) {
  int i = blockIdx.x * 256 + threadIdx.x;          // 786,432 = 1536*512
  int h = i & 511, j = i >> 9;
  int qkv = j >> 9, g = (j >> 6) & 7, d = j & 63;
  const float* W = (qkv == 0) ? Wq : ((qkv == 1) ? Wk : Wv);
  wcat[i] = (bf16)W[((g << 9) + h) * 64 + d];      // wcat[j][h] = W[g][h][d]
}

__global__ void prep_wo_kernel(const float* __restrict__ Wo, bf16* __restrict__ wot) {
  int i = blockIdx.x * 256 + threadIdx.x;          // 262,144
  int k = i & 511, n = i >> 9;
  wot[i] = (bf16)Wo[(k << 9) + n];                 // wot[n][k] = Wo[k][n]
}

// ---------- GEMM: C = A[M,K] * Bt[N,K]^T, bf16 in, f32 acc ----------
template <int MODE>
__global__ __launch_bounds__(256, 2) void gemm_bt_kernel(
    const bf16* __restrict__ A, const bf16* __restrict__ Bt, int Kdim, int Ndim,
    float* __restrict__ Cf, bf16* __restrict__ Qo, bf16* __restrict__ Ko,
    bf16* __restrict__ Vto) {
  __shared__ bf16 lA[128 * 32];
  __shared__ bf16 lB[128 * 32];
  const int t = threadIdx.x;
  const int w = t >> 6;
  const int lane = t & 63;
  const int lhi = lane >> 4, llo = lane & 15;
  const int m0 = blockIdx.y * 128, n0 = blockIdx.x * 128;
  const int wr = (w >> 1) * 64, wc = (w & 1) * 64;

  f32x4 acc[4][4] = {};
  const int nkt = Kdim >> 5;
  for (int kt = 0; kt < nkt; ++kt) {
#pragma unroll
    for (int c = 0; c < 2; ++c) {
      int u = c * 256 + t;
      const bf16* ga = A + (size_t)(m0 + (u >> 2)) * Kdim + kt * 32 + (u & 3) * 8;
      gload16(ga, &lA[c * 2048 + w * 512]);
      const bf16* gb = Bt + (size_t)(n0 + (u >> 2)) * Kdim + kt * 32 + (u & 3) * 8;
      gload16(gb, &lB[c * 2048 + w * 512]);
    }
    __syncthreads();
    bf16x8 af[4], bfr[4];
#pragma unroll
    for (int i = 0; i < 4; ++i) {
      af[i] = *(const bf16x8*)&lA[(wr + i * 16 + llo) * 32 + lhi * 8];
      bfr[i] = *(const bf16x8*)&lB[(wc + i * 16 + llo) * 32 + lhi * 8];
    }
#pragma unroll
    for (int i = 0; i < 4; ++i)
#pragma unroll
      for (int j = 0; j < 4; ++j)
        acc[i][j] = __builtin_amdgcn_mfma_f32_16x16x32_bf16(af[i], bfr[j], acc[i][j], 0, 0, 0);
    __syncthreads();
  }

#pragma unroll
  for (int i = 0; i < 4; ++i) {
    int row = m0 + wr + i * 16 + lhi * 4;
#pragma unroll
    for (int j = 0; j < 4; ++j) {
      int col = n0 + wc + j * 16 + llo;
#pragma unroll
      for (int r = 0; r < 4; ++r) {
        float v = acc[i][j][r];
        int rr = row + r;
        if (MODE == 0) {
          int qkv = col >> 9, g = (col >> 6) & 7, d = col & 63;
          bf16 bv = (bf16)v;
          if (qkv == 0)
            Qo[((size_t)g * 8192 + rr) * 64 + d] = bv;
          else if (qkv == 1)
            Ko[((size_t)g * 8192 + rr) * 64 + d] = bv;
          else {
            int b = rr >> 9, n = rr & 511;
            Vto[(((size_t)g * 16 + b) * 64 + d) * 512 + n] = bv;
          }
        } else {
          Cf[(size_t)rr * Ndim + col] = v;
        }
      }
    }
  }
}

// ---------- fused attention ----------
// grid (8 qtiles, 16 batch, 8 heads), 256 threads (4 waves x 16 q-rows)
// KVBLK=64, LDS = lK(8KB)+lV(8KB). S^T trick: mfma(K,Q) -> lane owns q=llo.
// P never touches LDS: A-frag assembled via cvt_pk + permlane swaps.
// Raw s_barrier (lgkm-only drain) keeps edge/KV prefetch loads in flight.
__global__ __launch_bounds__(256, 4) void attn_kernel(
    const bf16* __restrict__ Qa, const bf16* __restrict__ Ka,
    const bf16* __restrict__ Vta, const float* __restrict__ edge,
    bf16* __restrict__ Oatt) {
  __shared__ bf16 lK[64 * 64];
  __shared__ bf16 lV[64 * 64];
  const int t = threadIdx.x, w = t >> 6, lane = t & 63;
  const int lhi = lane >> 4, llo = lane & 15;
  const int qt = blockIdx.x, b = blockIdx.y, g = blockIdx.z;
  const int q0 = qt * 64 + w * 16;
  const bf16* Qg = Qa + ((size_t)g * 8192 + b * 512) * 64;
  const bf16* Kg = Ka + ((size_t)g * 8192 + b * 512) * 64;
  const bf16* Vg = Vta + ((size_t)g * 16 + b) * (64 * 512);
  const float* eg = edge + ((size_t)g * 16 + b) * (512 * 512);

  // Q fragments (B-operand layout: lane col = llo = q-row)
  bf16x8 qf[2];
#pragma unroll
  for (int ks = 0; ks < 2; ++ks)
    qf[ks] = *(const bf16x8*)(Qg + (size_t)(q0 + llo) * 64 + ks * 32 + lhi * 8);

  f32x4 oacc[4] = {};
  float mrow = -3e38f, lrow = 0.f;

  // staging chunk coords (constant per thread): u = i*256 + t -> (r, c)
  const int r0c = t >> 3, c0c = (t & 7) * 8;
  const int r1c = (256 + t) >> 3, c1c = c0c;

  // prologue: load KV tile 0 into regs
  bf16x8 kcur[2], vcur[2], knxt[2], vnxt[2];
  kcur[0] = *(const bf16x8*)(Kg + (size_t)r0c * 64 + c0c);
  kcur[1] = *(const bf16x8*)(Kg + (size_t)r1c * 64 + c1c);
  vcur[0] = *(const bf16x8*)(Vg + (size_t)r0c * 512 + c0c);
  vcur[1] = *(const bf16x8*)(Vg + (size_t)r1c * 512 + c1c);

  for (int it = 0; it < 8; ++it) {
    const int kv0 = it * 64;
    // ---- stage regs -> LDS (swizzled) ----
    *(bf16x8*)&lK[(r0c * 64 + c0c) ^ ((r0c & 7) << 3)] = kcur[0];
    *(bf16x8*)&lK[(r1c * 64 + c1c) ^ ((r1c & 7) << 3)] = kcur[1];
    *(bf16x8*)&lV[(r0c * 64 + c0c) ^ ((r0c & 7) << 3)] = vcur[0];
    *(bf16x8*)&lV[(r1c * 64 + c1c) ^ ((r1c & 7) << 3)] = vcur[1];
    // ---- prefetch next KV tile into regs (stays in flight through barriers) ----
    if (it < 7) {
      const int kvn = kv0 + 64;
      knxt[0] = *(const bf16x8*)(Kg + (size_t)(kvn + r0c) * 64 + c0c);
      knxt[1] = *(const bf16x8*)(Kg + (size_t)(kvn + r1c) * 64 + c1c);
      vnxt[0] = *(const bf16x8*)(Vg + (size_t)r0c * 512 + kvn + c0c);
      vnxt[1] = *(const bf16x8*)(Vg + (size_t)r1c * 512 + kvn + c1c);
    }
    // ---- edge bias loads for this tile (consumed after QK^T) ----
    f32x4 ef[4];
#pragma unroll
    for (int ni = 0; ni < 4; ++ni)
      ef[ni] = *(const f32x4*)(eg + (size_t)(q0 + llo) * 512 + kv0 + ni * 16 + lhi * 4);

    asm volatile("s_waitcnt lgkmcnt(0)" ::: "memory");
    __builtin_amdgcn_sched_barrier(0);
    __builtin_amdgcn_s_barrier();
    __builtin_amdgcn_sched_barrier(0);

    // ---- S^T = K Q^T : sc[ni][r] = S[q=llo][kv = ni*16 + lhi*4 + r] ----
    f32x4 sc[4] = {};
#pragma unroll
    for (int ks = 0; ks < 2; ++ks) {
      bf16x8 kf[4];
#pragma unroll
      for (int ni = 0; ni < 4; ++ni) {
        int row = ni * 16 + llo;
        kf[ni] = *(const bf16x8*)&lK[(row * 64 + ks * 32 + lhi * 8) ^ ((row & 7) << 3)];
      }
#pragma unroll
      for (int ni = 0; ni < 4; ++ni)
        sc[ni] = __builtin_amdgcn_mfma_f32_16x16x32_bf16(kf[ni], qf[ks], sc[ni], 0, 0, 0);
    }

    // ---- edge add + online softmax (reduce over lhi: 2 shfls) ----
    float mx = -3e38f;
#pragma unroll
    for (int ni = 0; ni < 4; ++ni)
#pragma unroll
      for (int r = 0; r < 4; ++r) {
        float sv = fmaf(ALPHA_, sc[ni][r], ef[ni][r]);
        sc[ni][r] = sv;
        mx = fmaxf(mx, sv);
      }
    mx = fmaxf(mx, __shfl_xor(mx, 16));
    mx = fmaxf(mx, __shfl_xor(mx, 32));
    float mnew = fmaxf(mrow, mx);
    float s = __expf(mrow - mnew);
    mrow = mnew;
    float rsum = 0.f;
#pragma unroll
    for (int ni = 0; ni < 4; ++ni)
#pragma unroll
      for (int r = 0; r < 4; ++r) {
        float p = __expf(sc[ni][r] - mnew);
        sc[ni][r] = p;
        rsum += p;
      }
    rsum += __shfl_xor(rsum, 16);
    rsum += __shfl_xor(rsum, 32);
    lrow = lrow * s + rsum;

    // rescale O accumulator (row r needs scale of q-row lhi*4+r, held at llo=lhi*4+r)
#pragma unroll
    for (int r = 0; r < 4; ++r) {
      float sq = __shfl(s, (lane & 48) | (lhi * 4 + r));
#pragma unroll
      for (int nc = 0; nc < 4; ++nc) oacc[nc][r] *= sq;
    }

    // ---- P A-frag via cvt_pk + permlane swaps; O += P V ----
#pragma unroll
    for (int ks2 = 0; ks2 < 2; ++ks2) {
      const int n0 = ks2 * 2, n1 = n0 + 1;
      unsigned xa, xb, ya, yb;
      asm("v_cvt_pk_bf16_f32 %0, %1, %2" : "=v"(xa) : "v"(sc[n0][0]), "v"(sc[n0][1]));
      asm("v_cvt_pk_bf16_f32 %0, %1, %2" : "=v"(xb) : "v"(sc[n0][2]), "v"(sc[n0][3]));
      asm("v_cvt_pk_bf16_f32 %0, %1, %2" : "=v"(ya) : "v"(sc[n1][0]), "v"(sc[n1][1]));
      asm("v_cvt_pk_bf16_f32 %0, %1, %2" : "=v"(yb) : "v"(sc[n1][2]), "v"(sc[n1][3]));
      asm("v_permlane32_swap_b32 %0, %1" : "+v"(xa), "+v"(ya));
      asm("v_permlane16_swap_b32 %0, %1" : "+v"(xa), "+v"(ya));
      asm("v_permlane32_swap_b32 %0, %1" : "+v"(xb), "+v"(yb));
      asm("v_permlane16_swap_b32 %0, %1" : "+v"(xb), "+v"(yb));
      union { unsigned wd[4]; bf16x8 v; } fu;
      fu.wd[0] = xa; fu.wd[1] = xb; fu.wd[2] = ya; fu.wd[3] = yb;
      bf16x8 pf = fu.v;

      bf16x8 vf[4];
#pragma unroll
      for (int nc = 0; nc < 4; ++nc) {
        int row = nc * 16 + llo;
        vf[nc] = *(const bf16x8*)&lV[(row * 64 + ks2 * 32 + lhi * 8) ^ ((row & 7) << 3)];
      }
#pragma unroll
      for (int nc = 0; nc < 4; ++nc)
        oacc[nc] = __builtin_amdgcn_mfma_f32_16x16x32_bf16(pf, vf[nc], oacc[nc], 0, 0, 0);
    }

    __builtin_amdgcn_sched_barrier(0);
    __builtin_amdgcn_s_barrier();
    __builtin_amdgcn_sched_barrier(0);

    if (it < 7) {
      kcur[0] = knxt[0]; kcur[1] = knxt[1];
      vcur[0] = vnxt[0]; vcur[1] = vnxt[1];
    }
  }

  // ---- normalize + write Oatt [b*512+q][g*64+d] ----
  float rcpl = 1.0f / lrow;
#pragma unroll
  for (int r = 0; r < 4; ++r) {
    float lr = __shfl(rcpl, (lane & 48) | (lhi * 4 + r));
    int qrow = q0 + lhi * 4 + r;
#pragma unroll
    for (int nc = 0; nc < 4; ++nc) {
      float ov = oacc[nc][r] * lr;
      Oatt[((size_t)b * 512 + qrow) * 512 + g * 64 + nc * 16 + llo] = (bf16)ov;
    }
  }
}

// ---------- launch ----------
extern "C" void kernel_launch(void* const* d_in, const int* in_sizes, int n_in,
                              void* d_out, int out_size, void* d_ws, size_t ws_size,
                              hipStream_t stream) {
  (void)in_sizes; (void)n_in; (void)out_size; (void)ws_size;
  const float* x = (const float*)d_in[0];
  const float* edge = (const float*)d_in[1];
  const float* Wq = (const float*)d_in[2];
  const float* Wk = (const float*)d_in[3];
  const float* Wv = (const float*)d_in[4];
  const float* Wo = (const float*)d_in[5];
  float* out = (float*)d_out;

  char* ws = (char*)d_ws;
  bf16* xb   = (bf16*)(ws + 0);
  bf16* wcat = (bf16*)(ws + 8388608);
  bf16* wot  = (bf16*)(ws + 9961472);
  bf16* Qa   = (bf16*)(ws + 10485760);
  bf16* Ka   = (bf16*)(ws + 18874368);
  bf16* Vta  = (bf16*)(ws + 27262976);
  bf16* Oatt = (bf16*)(ws + 35651584);

  cast_x_kernel<<<4096, 256, 0, stream>>>(x, xb);
  prep_w_kernel<<<3072, 256, 0, stream>>>(Wq, Wk, Wv, wcat);
  prep_wo_kernel<<<1024, 256, 0, stream>>>(Wo, wot);

  // QKV: A=xb [8192,512], Bt=wcat [1536,512]
  gemm_bt_kernel<0><<<dim3(12, 64), 256, 0, stream>>>(xb, wcat, 512, 1536,
                                                      nullptr, Qa, Ka, Vta);
  // fused attention
  attn_kernel<<<dim3(8, 16, 8), 256, 0, stream>>>(Qa, Ka, Vta, edge, Oatt);
  // output projection: A=Oatt [8192,512], Bt=wot [512,512] -> f32 out
  gemm_bt_kernel<1><<<dim3(4, 64), 256, 0, stream>>>(Oatt, wot, 512, 512,
                                                     out, nullptr, nullptr, nullptr);
}

// Round 4
// 106.795 us; speedup vs baseline: 1.5876x; 1.0127x over previous
//
#include <hip/hip_runtime.h>

// ---------- types ----------
typedef __bf16 bf16;
typedef __bf16 bf16x4 __attribute__((ext_vector_type(4)));
typedef __bf16 bf16x8 __attribute__((ext_vector_type(8)));
typedef float f32x4 __attribute__((ext_vector_type(4)));

#define ALPHA_ 0.125f   // 1/sqrt(64)

// H=8 heads, B=16, N=512, HID=512, D=64, M = B*N = 8192
// ws layout (bytes):
//   xb    [8192][512] bf16             @ 0          (8,388,608)
//   wcat  [1536][512] bf16 (B^T)       @ 8388608    (1,572,864)
//   wot   [512][512]  bf16 (Wo^T)      @ 9961472    (524,288)
//   Q     [8][8192][64] bf16           @ 10485760   (8,388,608)
//   K     [8][8192][64] bf16           @ 18874368   (8,388,608)
//   Vt    [8][16][64][512] bf16        @ 27262976   (8,388,608)
//   Oatt  [8192][512] bf16             @ 35651584   (8,388,608)

struct FalseT { static constexpr bool value = false; };
struct TrueT  { static constexpr bool value = true;  };

__device__ __forceinline__ void gload16(const void* g, void* l) {
  __builtin_amdgcn_global_load_lds((__attribute__((address_space(1))) void*)(g),
                                   (__attribute__((address_space(3))) void*)(l),
                                   16, 0, 0);
}

// ---------- prep kernels ----------
__global__ void cast_x_kernel(const float* __restrict__ x, bf16* __restrict__ xb) {
  int i = blockIdx.x * 256 + threadIdx.x;
  float4 v = ((const float4*)x)[i];
  bf16x4 o = {(bf16)v.x, (bf16)v.y, (bf16)v.z, (bf16)v.w};
  ((bf16x4*)xb)[i] = o;
}

__global__ void prep_w_kernel(const float* __restrict__ Wq, const float* __restrict__ Wk,
                              const float* __restrict__ Wv, bf16* __restrict__ wcat) {
  int i = blockIdx.x * 256 + threadIdx.x;          // 786,432 = 1536*512
  int h = i & 511, j = i >> 9;
  int qkv = j >> 9, g = (j >> 6) & 7, d = j & 63;
  const float* W = (qkv == 0) ? Wq : ((qkv == 1) ? Wk : Wv);
  wcat[i] = (bf16)W[((g << 9) + h) * 64 + d];      // wcat[j][h] = W[g][h][d]
}

__global__ void prep_wo_kernel(const float* __restrict__ Wo, bf16* __restrict__ wot) {
  int i = blockIdx.x * 256 + threadIdx.x;          // 262,144
  int k = i & 511, n = i >> 9;
  wot[i] = (bf16)Wo[(k << 9) + n];                 // wot[n][k] = Wo[k][n]
}

// ---------- GEMM: C = A[M,K] * Bt[N,K]^T, bf16 in, f32 acc ----------
template <int MODE>
__global__ __launch_bounds__(256, 2) void gemm_bt_kernel(
    const bf16* __restrict__ A, const bf16* __restrict__ Bt, int Kdim, int Ndim,
    float* __restrict__ Cf, bf16* __restrict__ Qo, bf16* __restrict__ Ko,
    bf16* __restrict__ Vto) {
  __shared__ bf16 lA[128 * 32];
  __shared__ bf16 lB[128 * 32];
  const int t = threadIdx.x;
  const int w = t >> 6;
  const int lane = t & 63;
  const int lhi = lane >> 4, llo = lane & 15;
  const int m0 = blockIdx.y * 128, n0 = blockIdx.x * 128;
  const int wr = (w >> 1) * 64, wc = (w & 1) * 64;

  f32x4 acc[4][4] = {};
  const int nkt = Kdim >> 5;
  for (int kt = 0; kt < nkt; ++kt) {
#pragma unroll
    for (int c = 0; c < 2; ++c) {
      int u = c * 256 + t;
      const bf16* ga = A + (size_t)(m0 + (u >> 2)) * Kdim + kt * 32 + (u & 3) * 8;
      gload16(ga, &lA[c * 2048 + w * 512]);
      const bf16* gb = Bt + (size_t)(n0 + (u >> 2)) * Kdim + kt * 32 + (u & 3) * 8;
      gload16(gb, &lB[c * 2048 + w * 512]);
    }
    __syncthreads();
    bf16x8 af[4], bfr[4];
#pragma unroll
    for (int i = 0; i < 4; ++i) {
      af[i] = *(const bf16x8*)&lA[(wr + i * 16 + llo) * 32 + lhi * 8];
      bfr[i] = *(const bf16x8*)&lB[(wc + i * 16 + llo) * 32 + lhi * 8];
    }
#pragma unroll
    for (int i = 0; i < 4; ++i)
#pragma unroll
      for (int j = 0; j < 4; ++j)
        acc[i][j] = __builtin_amdgcn_mfma_f32_16x16x32_bf16(af[i], bfr[j], acc[i][j], 0, 0, 0);
    __syncthreads();
  }

#pragma unroll
  for (int i = 0; i < 4; ++i) {
    int row = m0 + wr + i * 16 + lhi * 4;
#pragma unroll
    for (int j = 0; j < 4; ++j) {
      int col = n0 + wc + j * 16 + llo;
#pragma unroll
      for (int r = 0; r < 4; ++r) {
        float v = acc[i][j][r];
        int rr = row + r;
        if (MODE == 0) {
          int qkv = col >> 9, g = (col >> 6) & 7, d = col & 63;
          bf16 bv = (bf16)v;
          if (qkv == 0)
            Qo[((size_t)g * 8192 + rr) * 64 + d] = bv;
          else if (qkv == 1)
            Ko[((size_t)g * 8192 + rr) * 64 + d] = bv;
          else {
            int b = rr >> 9, n = rr & 511;
            Vto[(((size_t)g * 16 + b) * 64 + d) * 512 + n] = bv;
          }
        } else {
          Cf[(size_t)rr * Ndim + col] = v;
        }
      }
    }
  }
}

// ---------- fused attention ----------
// grid (8 qtiles, 16 batch, 8 heads), 256 threads (4 waves x 16 q-rows)
// KVBLK=64. Double-buffered LDS KV staged via global_load_lds with
// PRE-SWIZZLED global source (linear LDS dest); edge bias double-buffered
// in regs, issued one tile ahead; counted vmcnt(8) keeps 8 loads in flight
// across both barriers (T3+T4). S^T trick: mfma(K,Q) -> lane owns q=llo;
// P assembled in-register via cvt_pk + permlane swaps (T12).
__global__ __launch_bounds__(256, 4) void attn_kernel(
    const bf16* __restrict__ Qa, const bf16* __restrict__ Ka,
    const bf16* __restrict__ Vta, const float* __restrict__ edge,
    bf16* __restrict__ Oatt) {
  __shared__ bf16 lK[2][64 * 64];
  __shared__ bf16 lV[2][64 * 64];
  const int t = threadIdx.x, w = t >> 6, lane = t & 63;
  const int lhi = lane >> 4, llo = lane & 15;
  const int qt = blockIdx.x, b = blockIdx.y, g = blockIdx.z;
  const int q0 = qt * 64 + w * 16;
  const bf16* Qg = Qa + ((size_t)g * 8192 + b * 512) * 64;
  const bf16* Kg = Ka + ((size_t)g * 8192 + b * 512) * 64;
  const bf16* Vg = Vta + ((size_t)g * 16 + b) * (64 * 512);
  const float* eg = edge + ((size_t)g * 16 + b) * (512 * 512);

  // Q fragments (B-operand layout: lane col = llo = q-row)
  bf16x8 qf[2];
#pragma unroll
  for (int ks = 0; ks < 2; ++ks)
    qf[ks] = *(const bf16x8*)(Qg + (size_t)(q0 + llo) * 64 + ks * 32 + lhi * 8);

  f32x4 oacc[4] = {};
  float mrow = -3e38f, lrow = 0.f;

  // staging coords: chunk u = j*256 + t; row = u>>3, col-chunk = t&7.
  // pre-swizzled SOURCE col-chunk = (t&7) ^ (row&7); note (r0&7)==(r1&7).
  const int r0 = t >> 3;          // rows 0..31 (issue 0)
  const int r1 = r0 + 32;         // rows 32..63 (issue 1)
  const int cs = (((t & 7) ^ (r0 & 7)) << 3);  // swizzled source col (elems)

  // edge double buffer
  f32x4 ef[4], efn[4];

  // ---- prologue: tile 0 ----
  gload16(Kg + (size_t)r0 * 64 + cs, &lK[0][w * 512]);
  gload16(Kg + (size_t)r1 * 64 + cs, &lK[0][2048 + w * 512]);
  gload16(Vg + (size_t)r0 * 512 + cs, &lV[0][w * 512]);
  gload16(Vg + (size_t)r1 * 512 + cs, &lV[0][2048 + w * 512]);
#pragma unroll
  for (int ni = 0; ni < 4; ++ni)
    ef[ni] = *(const f32x4*)(eg + (size_t)(q0 + llo) * 512 + ni * 16 + lhi * 4);

  auto iter_body = [&](int it, auto LASTC) {
    constexpr bool LAST = decltype(LASTC)::value;
    const int kv0 = it * 64;
    const int cur = it & 1;
    if constexpr (!LAST) {
      const int nxt = cur ^ 1;
      const int kvn = kv0 + 64;
      gload16(Kg + (size_t)(kvn + r0) * 64 + cs, &lK[nxt][w * 512]);
      gload16(Kg + (size_t)(kvn + r1) * 64 + cs, &lK[nxt][2048 + w * 512]);
      gload16(Vg + (size_t)r0 * 512 + kvn + cs, &lV[nxt][w * 512]);
      gload16(Vg + (size_t)r1 * 512 + kvn + cs, &lV[nxt][2048 + w * 512]);
#pragma unroll
      for (int ni = 0; ni < 4; ++ni)
        efn[ni] = *(const f32x4*)(eg + (size_t)(q0 + llo) * 512 + kvn + ni * 16 + lhi * 4);
    }
    // wait: tile-t loads (8 oldest) done; tile-t+1 loads (8) stay in flight
    if constexpr (!LAST)
      asm volatile("s_waitcnt vmcnt(8)" ::: "memory");
    else
      asm volatile("s_waitcnt vmcnt(0)" ::: "memory");
    __builtin_amdgcn_sched_barrier(0);
    __builtin_amdgcn_s_barrier();
    __builtin_amdgcn_sched_barrier(0);

    // ---- S^T = K Q^T : sc[ni][r] = S[q=llo][kv = ni*16 + lhi*4 + r] ----
    f32x4 sc[4] = {};
    __builtin_amdgcn_s_setprio(1);
#pragma unroll
    for (int ks = 0; ks < 2; ++ks) {
      bf16x8 kf[4];
#pragma unroll
      for (int ni = 0; ni < 4; ++ni) {
        int row = ni * 16 + llo;
        kf[ni] = *(const bf16x8*)&lK[cur][(row * 64 + ks * 32 + lhi * 8) ^ ((row & 7) << 3)];
      }
#pragma unroll
      for (int ni = 0; ni < 4; ++ni)
        sc[ni] = __builtin_amdgcn_mfma_f32_16x16x32_bf16(kf[ni], qf[ks], sc[ni], 0, 0, 0);
    }
    __builtin_amdgcn_s_setprio(0);

    // ---- edge add + online softmax (reduce over lhi: 2 shfls) ----
    float mx = -3e38f;
#pragma unroll
    for (int ni = 0; ni < 4; ++ni)
#pragma unroll
      for (int r = 0; r < 4; ++r) {
        float sv = fmaf(ALPHA_, sc[ni][r], ef[ni][r]);
        sc[ni][r] = sv;
        mx = fmaxf(mx, sv);
      }
    mx = fmaxf(mx, __shfl_xor(mx, 16));
    mx = fmaxf(mx, __shfl_xor(mx, 32));
    float mnew = fmaxf(mrow, mx);
    float s = __expf(mrow - mnew);
    mrow = mnew;
    float rsum = 0.f;
#pragma unroll
    for (int ni = 0; ni < 4; ++ni)
#pragma unroll
      for (int r = 0; r < 4; ++r) {
        float p = __expf(sc[ni][r] - mnew);
        sc[ni][r] = p;
        rsum += p;
      }
    rsum += __shfl_xor(rsum, 16);
    rsum += __shfl_xor(rsum, 32);
    lrow = lrow * s + rsum;

    // rescale O accumulator (row r needs scale of q-row lhi*4+r, held at llo=lhi*4+r)
#pragma unroll
    for (int r = 0; r < 4; ++r) {
      float sq = __shfl(s, (lane & 48) | (lhi * 4 + r));
#pragma unroll
      for (int nc = 0; nc < 4; ++nc) oacc[nc][r] *= sq;
    }

    // ---- P A-frag via cvt_pk + permlane swaps; O += P V ----
    __builtin_amdgcn_s_setprio(1);
#pragma unroll
    for (int ks2 = 0; ks2 < 2; ++ks2) {
      const int n0 = ks2 * 2, n1 = n0 + 1;
      unsigned xa, xb, ya, yb;
      asm("v_cvt_pk_bf16_f32 %0, %1, %2" : "=v"(xa) : "v"(sc[n0][0]), "v"(sc[n0][1]));
      asm("v_cvt_pk_bf16_f32 %0, %1, %2" : "=v"(xb) : "v"(sc[n0][2]), "v"(sc[n0][3]));
      asm("v_cvt_pk_bf16_f32 %0, %1, %2" : "=v"(ya) : "v"(sc[n1][0]), "v"(sc[n1][1]));
      asm("v_cvt_pk_bf16_f32 %0, %1, %2" : "=v"(yb) : "v"(sc[n1][2]), "v"(sc[n1][3]));
      asm("v_permlane32_swap_b32 %0, %1" : "+v"(xa), "+v"(ya));
      asm("v_permlane16_swap_b32 %0, %1" : "+v"(xa), "+v"(ya));
      asm("v_permlane32_swap_b32 %0, %1" : "+v"(xb), "+v"(yb));
      asm("v_permlane16_swap_b32 %0, %1" : "+v"(xb), "+v"(yb));
      union { unsigned wd[4]; bf16x8 v; } fu;
      fu.wd[0] = xa; fu.wd[1] = xb; fu.wd[2] = ya; fu.wd[3] = yb;
      bf16x8 pf = fu.v;

      bf16x8 vf[4];
#pragma unroll
      for (int nc = 0; nc < 4; ++nc) {
        int row = nc * 16 + llo;
        vf[nc] = *(const bf16x8*)&lV[cur][(row * 64 + ks2 * 32 + lhi * 8) ^ ((row & 7) << 3)];
      }
#pragma unroll
      for (int nc = 0; nc < 4; ++nc)
        oacc[nc] = __builtin_amdgcn_mfma_f32_16x16x32_bf16(pf, vf[nc], oacc[nc], 0, 0, 0);
    }
    __builtin_amdgcn_s_setprio(0);

    if constexpr (!LAST) {
      // barrier B: all waves done reading buf[cur] before next iter's
      // gload_lds (issued after this point) can overwrite it
      __builtin_amdgcn_sched_barrier(0);
      __builtin_amdgcn_s_barrier();
      __builtin_amdgcn_sched_barrier(0);
#pragma unroll
      for (int ni = 0; ni < 4; ++ni) ef[ni] = efn[ni];
    }
  };

  for (int it = 0; it < 7; ++it) iter_body(it, FalseT{});
  iter_body(7, TrueT{});

  // ---- normalize + write Oatt [b*512+q][g*64+d] ----
  float rcpl = 1.0f / lrow;
#pragma unroll
  for (int r = 0; r < 4; ++r) {
    float lr = __shfl(rcpl, (lane & 48) | (lhi * 4 + r));
    int qrow = q0 + lhi * 4 + r;
#pragma unroll
    for (int nc = 0; nc < 4; ++nc) {
      float ov = oacc[nc][r] * lr;
      Oatt[((size_t)b * 512 + qrow) * 512 + g * 64 + nc * 16 + llo] = (bf16)ov;
    }
  }
}

// ---------- launch ----------
extern "C" void kernel_launch(void* const* d_in, const int* in_sizes, int n_in,
                              void* d_out, int out_size, void* d_ws, size_t ws_size,
                              hipStream_t stream) {
  (void)in_sizes; (void)n_in; (void)out_size; (void)ws_size;
  const float* x = (const float*)d_in[0];
  const float* edge = (const float*)d_in[1];
  const float* Wq = (const float*)d_in[2];
  const float* Wk = (const float*)d_in[3];
  const float* Wv = (const float*)d_in[4];
  const float* Wo = (const float*)d_in[5];
  float* out = (float*)d_out;

  char* ws = (char*)d_ws;
  bf16* xb   = (bf16*)(ws + 0);
  bf16* wcat = (bf16*)(ws + 8388608);
  bf16* wot  = (bf16*)(ws + 9961472);
  bf16* Qa   = (bf16*)(ws + 10485760);
  bf16* Ka   = (bf16*)(ws + 18874368);
  bf16* Vta  = (bf16*)(ws + 27262976);
  bf16* Oatt = (bf16*)(ws + 35651584);

  cast_x_kernel<<<4096, 256, 0, stream>>>(x, xb);
  prep_w_kernel<<<3072, 256, 0, stream>>>(Wq, Wk, Wv, wcat);
  prep_wo_kernel<<<1024, 256, 0, stream>>>(Wo, wot);

  // QKV: A=xb [8192,512], Bt=wcat [1536,512]
  gemm_bt_kernel<0><<<dim3(12, 64), 256, 0, stream>>>(xb, wcat, 512, 1536,
                                                      nullptr, Qa, Ka, Vta);
  // fused attention
  attn_kernel<<<dim3(8, 16, 8), 256, 0, stream>>>(Qa, Ka, Vta, edge, Oatt);
  // output projection: A=Oatt [8192,512], Bt=wot [512,512] -> f32 out
  gemm_bt_kernel<1><<<dim3(4, 64), 256, 0, stream>>>(Oatt, wot, 512, 512,
                                                     out, nullptr, nullptr, nullptr);
}

// Round 5
// 106.176 us; speedup vs baseline: 1.5969x; 1.0058x over previous
//
#include <hip/hip_runtime.h>

// ---------- types ----------
typedef __bf16 bf16;
typedef __bf16 bf16x4 __attribute__((ext_vector_type(4)));
typedef __bf16 bf16x8 __attribute__((ext_vector_type(8)));
typedef float f32x4 __attribute__((ext_vector_type(4)));

#define ALPHA_ 0.125f   // 1/sqrt(64)

// H=8 heads, B=16, N=512, HID=512, D=64, M = B*N = 8192
// ws layout (bytes):
//   xb    [8192][512] bf16             @ 0          (8,388,608)
//   wcat  [1536][512] bf16 (B^T)       @ 8388608    (1,572,864)
//   wot   [512][512]  bf16 (Wo^T)      @ 9961472    (524,288)
//   Q     [8][8192][64] bf16           @ 10485760   (8,388,608)
//   K     [8][8192][64] bf16           @ 18874368   (8,388,608)
//   Vt    [8][16][64][512] bf16        @ 27262976   (8,388,608)
//   Oatt  [8192][512] bf16             @ 35651584   (8,388,608)

__device__ __forceinline__ void gload16(const void* g, void* l) {
  __builtin_amdgcn_global_load_lds((__attribute__((address_space(1))) void*)(g),
                                   (__attribute__((address_space(3))) void*)(l),
                                   16, 0, 0);
}

// ---------- prep kernels ----------
__global__ void cast_x_kernel(const float* __restrict__ x, bf16* __restrict__ xb) {
  int i = blockIdx.x * 256 + threadIdx.x;
  float4 v = ((const float4*)x)[i];
  bf16x4 o = {(bf16)v.x, (bf16)v.y, (bf16)v.z, (bf16)v.w};
  ((bf16x4*)xb)[i] = o;
}

__global__ void prep_w_kernel(const float* __restrict__ Wq, const float* __restrict__ Wk,
                              const float* __restrict__ Wv, bf16* __restrict__ wcat) {
  int i = blockIdx.x * 256 + threadIdx.x;          // 786,432 = 1536*512
  int h = i & 511, j = i >> 9;
  int qkv = j >> 9, g = (j >> 6) & 7, d = j & 63;
  const float* W = (qkv == 0) ? Wq : ((qkv == 1) ? Wk : Wv);
  wcat[i] = (bf16)W[((g << 9) + h) * 64 + d];      // wcat[j][h] = W[g][h][d]
}

__global__ void prep_wo_kernel(const float* __restrict__ Wo, bf16* __restrict__ wot) {
  int i = blockIdx.x * 256 + threadIdx.x;          // 262,144
  int k = i & 511, n = i >> 9;
  wot[i] = (bf16)Wo[(k << 9) + n];                 // wot[n][k] = Wo[k][n]
}

// ---------- GEMM: C = A[M,K] * Bt[N,K]^T, bf16 in, f32 acc ----------
template <int MODE>
__global__ __launch_bounds__(256, 2) void gemm_bt_kernel(
    const bf16* __restrict__ A, const bf16* __restrict__ Bt, int Kdim, int Ndim,
    float* __restrict__ Cf, bf16* __restrict__ Qo, bf16* __restrict__ Ko,
    bf16* __restrict__ Vto) {
  __shared__ bf16 lA[128 * 32];
  __shared__ bf16 lB[128 * 32];
  const int t = threadIdx.x;
  const int w = t >> 6;
  const int lane = t & 63;
  const int lhi = lane >> 4, llo = lane & 15;
  const int m0 = blockIdx.y * 128, n0 = blockIdx.x * 128;
  const int wr = (w >> 1) * 64, wc = (w & 1) * 64;

  f32x4 acc[4][4] = {};
  const int nkt = Kdim >> 5;
  for (int kt = 0; kt < nkt; ++kt) {
#pragma unroll
    for (int c = 0; c < 2; ++c) {
      int u = c * 256 + t;
      const bf16* ga = A + (size_t)(m0 + (u >> 2)) * Kdim + kt * 32 + (u & 3) * 8;
      gload16(ga, &lA[c * 2048 + w * 512]);
      const bf16* gb = Bt + (size_t)(n0 + (u >> 2)) * Kdim + kt * 32 + (u & 3) * 8;
      gload16(gb, &lB[c * 2048 + w * 512]);
    }
    __syncthreads();
    bf16x8 af[4], bfr[4];
#pragma unroll
    for (int i = 0; i < 4; ++i) {
      af[i] = *(const bf16x8*)&lA[(wr + i * 16 + llo) * 32 + lhi * 8];
      bfr[i] = *(const bf16x8*)&lB[(wc + i * 16 + llo) * 32 + lhi * 8];
    }
#pragma unroll
    for (int i = 0; i < 4; ++i)
#pragma unroll
      for (int j = 0; j < 4; ++j)
        acc[i][j] = __builtin_amdgcn_mfma_f32_16x16x32_bf16(af[i], bfr[j], acc[i][j], 0, 0, 0);
    __syncthreads();
  }

#pragma unroll
  for (int i = 0; i < 4; ++i) {
    int row = m0 + wr + i * 16 + lhi * 4;
#pragma unroll
    for (int j = 0; j < 4; ++j) {
      int col = n0 + wc + j * 16 + llo;
#pragma unroll
      for (int r = 0; r < 4; ++r) {
        float v = acc[i][j][r];
        int rr = row + r;
        if (MODE == 0) {
          int qkv = col >> 9, g = (col >> 6) & 7, d = col & 63;
          bf16 bv = (bf16)v;
          if (qkv == 0)
            Qo[((size_t)g * 8192 + rr) * 64 + d] = bv;
          else if (qkv == 1)
            Ko[((size_t)g * 8192 + rr) * 64 + d] = bv;
          else {
            int b = rr >> 9, n = rr & 511;
            Vto[(((size_t)g * 16 + b) * 64 + d) * 512 + n] = bv;
          }
        } else {
          Cf[(size_t)rr * Ndim + col] = v;
        }
      }
    }
  }
}

// ---------- fused attention ----------
// grid (8 qtiles, 16 batch, 8 heads), 256 threads (4 waves x 16 q-rows)
// KVBLK=64. Double-buffered LDS KV staged via global_load_lds with
// PRE-SWIZZLED global source (linear LDS dest). Edge bias in a 2-entry
// PARITY-INDEXED register buffer (fully unrolled loop -> static indices,
// NO register copy -> no in-order vmcnt drain). Counted vmcnt(8) keeps
// tile t+1's 8 loads in flight across the whole compute phase (T3+T4).
// S^T trick: mfma(K,Q) -> lane owns q=llo; P assembled in-register via
// cvt_pk + permlane swaps (T12).
__global__ __launch_bounds__(256, 4) void attn_kernel(
    const bf16* __restrict__ Qa, const bf16* __restrict__ Ka,
    const bf16* __restrict__ Vta, const float* __restrict__ edge,
    bf16* __restrict__ Oatt) {
  __shared__ bf16 lK[2][64 * 64];
  __shared__ bf16 lV[2][64 * 64];
  const int t = threadIdx.x, w = t >> 6, lane = t & 63;
  const int lhi = lane >> 4, llo = lane & 15;
  const int qt = blockIdx.x, b = blockIdx.y, g = blockIdx.z;
  const int q0 = qt * 64 + w * 16;
  const bf16* Qg = Qa + ((size_t)g * 8192 + b * 512) * 64;
  const bf16* Kg = Ka + ((size_t)g * 8192 + b * 512) * 64;
  const bf16* Vg = Vta + ((size_t)g * 16 + b) * (64 * 512);
  const float* eg = edge + ((size_t)g * 16 + b) * (512 * 512);

  // Q fragments (B-operand layout: lane col = llo = q-row)
  bf16x8 qf[2];
#pragma unroll
  for (int ks = 0; ks < 2; ++ks)
    qf[ks] = *(const bf16x8*)(Qg + (size_t)(q0 + llo) * 64 + ks * 32 + lhi * 8);

  f32x4 oacc[4] = {};
  float mrow = -3e38f, lrow = 0.f;

  // staging coords: row = (j*256+t)>>3; pre-swizzled SOURCE col-chunk
  const int r0 = t >> 3;          // rows 0..31 (issue 0)
  const int r1 = r0 + 32;         // rows 32..63 (issue 1), (r1&7)==(r0&7)
  const int cs = (((t & 7) ^ (r0 & 7)) << 3);

  // edge bias double buffer, parity-indexed (static after full unroll)
  f32x4 eb[2][4];

  // ---- prologue: tile 0 (8 vmem ops: 4 gload_lds + 4 edge) ----
  gload16(Kg + (size_t)r0 * 64 + cs, &lK[0][w * 512]);
  gload16(Kg + (size_t)r1 * 64 + cs, &lK[0][2048 + w * 512]);
  gload16(Vg + (size_t)r0 * 512 + cs, &lV[0][w * 512]);
  gload16(Vg + (size_t)r1 * 512 + cs, &lV[0][2048 + w * 512]);
#pragma unroll
  for (int ni = 0; ni < 4; ++ni)
    eb[0][ni] = *(const f32x4*)(eg + (size_t)(q0 + llo) * 512 + ni * 16 + lhi * 4);
  __builtin_amdgcn_sched_barrier(0);

#pragma unroll
  for (int it = 0; it < 8; ++it) {
    const int cur = it & 1, nxt = cur ^ 1;
    const int kv0 = it * 64;

    // ---- issue tile t+1 loads (stay in flight through both barriers) ----
    if (it < 7) {
      const int kvn = kv0 + 64;
      gload16(Kg + (size_t)(kvn + r0) * 64 + cs, &lK[nxt][w * 512]);
      gload16(Kg + (size_t)(kvn + r1) * 64 + cs, &lK[nxt][2048 + w * 512]);
      gload16(Vg + (size_t)r0 * 512 + kvn + cs, &lV[nxt][w * 512]);
      gload16(Vg + (size_t)r1 * 512 + kvn + cs, &lV[nxt][2048 + w * 512]);
#pragma unroll
      for (int ni = 0; ni < 4; ++ni)
        eb[nxt][ni] = *(const f32x4*)(eg + (size_t)(q0 + llo) * 512 + kvn + ni * 16 + lhi * 4);
    }
    // pin the 8 issues above the counted wait, then wait for tile t only
    __builtin_amdgcn_sched_barrier(0);
    if (it < 7)
      asm volatile("s_waitcnt vmcnt(8)" ::: "memory");
    else
      asm volatile("s_waitcnt vmcnt(0)" ::: "memory");
    __builtin_amdgcn_sched_barrier(0);
    __builtin_amdgcn_s_barrier();
    __builtin_amdgcn_sched_barrier(0);

    // ---- S^T = K Q^T : sc[ni][r] = S[q=llo][kv = ni*16 + lhi*4 + r] ----
    f32x4 sc[4] = {};
    __builtin_amdgcn_s_setprio(1);
#pragma unroll
    for (int ks = 0; ks < 2; ++ks) {
      bf16x8 kf[4];
#pragma unroll
      for (int ni = 0; ni < 4; ++ni) {
        int row = ni * 16 + llo;
        kf[ni] = *(const bf16x8*)&lK[cur][(row * 64 + ks * 32 + lhi * 8) ^ ((row & 7) << 3)];
      }
#pragma unroll
      for (int ni = 0; ni < 4; ++ni)
        sc[ni] = __builtin_amdgcn_mfma_f32_16x16x32_bf16(kf[ni], qf[ks], sc[ni], 0, 0, 0);
    }
    __builtin_amdgcn_s_setprio(0);

    // ---- edge add + online softmax (reduce over lhi: 2 shfls) ----
    float mx = -3e38f;
#pragma unroll
    for (int ni = 0; ni < 4; ++ni)
#pragma unroll
      for (int r = 0; r < 4; ++r) {
        float sv = fmaf(ALPHA_, sc[ni][r], eb[cur][ni][r]);
        sc[ni][r] = sv;
        mx = fmaxf(mx, sv);
      }
    mx = fmaxf(mx, __shfl_xor(mx, 16));
    mx = fmaxf(mx, __shfl_xor(mx, 32));
    float mnew = fmaxf(mrow, mx);
    float s = __expf(mrow - mnew);
    mrow = mnew;
    float rsum = 0.f;
#pragma unroll
    for (int ni = 0; ni < 4; ++ni)
#pragma unroll
      for (int r = 0; r < 4; ++r) {
        float p = __expf(sc[ni][r] - mnew);
        sc[ni][r] = p;
        rsum += p;
      }
    rsum += __shfl_xor(rsum, 16);
    rsum += __shfl_xor(rsum, 32);
    lrow = lrow * s + rsum;

    // rescale O accumulator (row r needs scale of q-row lhi*4+r, held at llo=lhi*4+r)
#pragma unroll
    for (int r = 0; r < 4; ++r) {
      float sq = __shfl(s, (lane & 48) | (lhi * 4 + r));
#pragma unroll
      for (int nc = 0; nc < 4; ++nc) oacc[nc][r] *= sq;
    }

    // ---- P A-frag via cvt_pk + permlane swaps; O += P V ----
    __builtin_amdgcn_s_setprio(1);
#pragma unroll
    for (int ks2 = 0; ks2 < 2; ++ks2) {
      const int n0 = ks2 * 2, n1 = n0 + 1;
      unsigned xa, xb, ya, yb;
      asm("v_cvt_pk_bf16_f32 %0, %1, %2" : "=v"(xa) : "v"(sc[n0][0]), "v"(sc[n0][1]));
      asm("v_cvt_pk_bf16_f32 %0, %1, %2" : "=v"(xb) : "v"(sc[n0][2]), "v"(sc[n0][3]));
      asm("v_cvt_pk_bf16_f32 %0, %1, %2" : "=v"(ya) : "v"(sc[n1][0]), "v"(sc[n1][1]));
      asm("v_cvt_pk_bf16_f32 %0, %1, %2" : "=v"(yb) : "v"(sc[n1][2]), "v"(sc[n1][3]));
      asm("v_permlane32_swap_b32 %0, %1" : "+v"(xa), "+v"(ya));
      asm("v_permlane16_swap_b32 %0, %1" : "+v"(xa), "+v"(ya));
      asm("v_permlane32_swap_b32 %0, %1" : "+v"(xb), "+v"(yb));
      asm("v_permlane16_swap_b32 %0, %1" : "+v"(xb), "+v"(yb));
      union { unsigned wd[4]; bf16x8 v; } fu;
      fu.wd[0] = xa; fu.wd[1] = xb; fu.wd[2] = ya; fu.wd[3] = yb;
      bf16x8 pf = fu.v;

      bf16x8 vf[4];
#pragma unroll
      for (int nc = 0; nc < 4; ++nc) {
        int row = nc * 16 + llo;
        vf[nc] = *(const bf16x8*)&lV[cur][(row * 64 + ks2 * 32 + lhi * 8) ^ ((row & 7) << 3)];
      }
#pragma unroll
      for (int nc = 0; nc < 4; ++nc)
        oacc[nc] = __builtin_amdgcn_mfma_f32_16x16x32_bf16(pf, vf[nc], oacc[nc], 0, 0, 0);
    }
    __builtin_amdgcn_s_setprio(0);

    if (it < 7) {
      // barrier B: all waves done reading buf[cur] before next iter's
      // gload_lds overwrites buf[nxt]'s partner (issued after this point)
      __builtin_amdgcn_sched_barrier(0);
      __builtin_amdgcn_s_barrier();
      __builtin_amdgcn_sched_barrier(0);
    }
  }

  // ---- normalize + write Oatt [b*512+q][g*64+d] ----
  float rcpl = 1.0f / lrow;
#pragma unroll
  for (int r = 0; r < 4; ++r) {
    float lr = __shfl(rcpl, (lane & 48) | (lhi * 4 + r));
    int qrow = q0 + lhi * 4 + r;
#pragma unroll
    for (int nc = 0; nc < 4; ++nc) {
      float ov = oacc[nc][r] * lr;
      Oatt[((size_t)b * 512 + qrow) * 512 + g * 64 + nc * 16 + llo] = (bf16)ov;
    }
  }
}

// ---------- launch ----------
extern "C" void kernel_launch(void* const* d_in, const int* in_sizes, int n_in,
                              void* d_out, int out_size, void* d_ws, size_t ws_size,
                              hipStream_t stream) {
  (void)in_sizes; (void)n_in; (void)out_size; (void)ws_size;
  const float* x = (const float*)d_in[0];
  const float* edge = (const float*)d_in[1];
  const float* Wq = (const float*)d_in[2];
  const float* Wk = (const float*)d_in[3];
  const float* Wv = (const float*)d_in[4];
  const float* Wo = (const float*)d_in[5];
  float* out = (float*)d_out;

  char* ws = (char*)d_ws;
  bf16* xb   = (bf16*)(ws + 0);
  bf16* wcat = (bf16*)(ws + 8388608);
  bf16* wot  = (bf16*)(ws + 9961472);
  bf16* Qa   = (bf16*)(ws + 10485760);
  bf16* Ka   = (bf16*)(ws + 18874368);
  bf16* Vta  = (bf16*)(ws + 27262976);
  bf16* Oatt = (bf16*)(ws + 35651584);

  cast_x_kernel<<<4096, 256, 0, stream>>>(x, xb);
  prep_w_kernel<<<3072, 256, 0, stream>>>(Wq, Wk, Wv, wcat);
  prep_wo_kernel<<<1024, 256, 0, stream>>>(Wo, wot);

  // QKV: A=xb [8192,512], Bt=wcat [1536,512]
  gemm_bt_kernel<0><<<dim3(12, 64), 256, 0, stream>>>(xb, wcat, 512, 1536,
                                                      nullptr, Qa, Ka, Vta);
  // fused attention
  attn_kernel<<<dim3(8, 16, 8), 256, 0, stream>>>(Qa, Ka, Vta, edge, Oatt);
  // output projection: A=Oatt [8192,512], Bt=wot [512,512] -> f32 out
  gemm_bt_kernel<1><<<dim3(4, 64), 256, 0, stream>>>(Oatt, wot, 512, 512,
                                                     out, nullptr, nullptr, nullptr);
}